// Round 1
// baseline (344.004 us; speedup 1.0000x reference)
//
#include <hip/hip_runtime.h>

// PAM module: B=4, C=512, N=64*64=4096, Cq=64.
// Stage 1 (proj_kernel): q,k,v = W@x + b via split-bf16 MFMA.
//   q,k stored transposed+split: qhi/qlo/khi/klo bf16 [B][N][64] (2 MB each)
//   v stored bf16 [B][C][N] (16 MB).  ws total = 24 MB.
// Stage 2 (attn_kernel): flash attention, 64-row Q panel per block, 8 waves,
//   each wave owns 64 channels of C for PV. Split-bf16 QK^T (3 MFMA terms),
//   online softmax (8 lanes per row), P round-trips LDS as bf16.

typedef float          f32x4  __attribute__((ext_vector_type(4)));
typedef short          bf16x8 __attribute__((ext_vector_type(8)));
typedef unsigned short u16x4  __attribute__((ext_vector_type(4)));
typedef unsigned short u16x8  __attribute__((ext_vector_type(8)));

#define MFMA16(a, b, c) __builtin_amdgcn_mfma_f32_16x16x32_bf16((a), (b), (c), 0, 0, 0)

__device__ __forceinline__ unsigned short bf16_rne(float f) {
    unsigned u = __builtin_bit_cast(unsigned, f);
    u += 0x7FFFu + ((u >> 16) & 1u);
    return (unsigned short)(u >> 16);
}
__device__ __forceinline__ float bf16_f(unsigned short h) {
    unsigned u = (unsigned)h << 16;
    return __builtin_bit_cast(float, u);
}

constexpr int BB = 4, CCH = 512, NS = 4096;

// ---------------------------------------------------------------------------
// Projection kernel. Grid: 256 blocks = b(4) x n-tile(64). Block: 512 thr.
// Wave w<4: q o-frag (w&3)*16..+15 (3-term split). Wave w>=4: same for k.
// All waves: v channels [64w, 64w+64).
// ---------------------------------------------------------------------------
__global__ __launch_bounds__(512, 1) void proj_kernel(
    const float* __restrict__ x,
    const float* __restrict__ Wq, const float* __restrict__ bq,
    const float* __restrict__ Wk, const float* __restrict__ bk,
    const float* __restrict__ Wv, const float* __restrict__ bv,
    unsigned short* __restrict__ qhi, unsigned short* __restrict__ qlo,
    unsigned short* __restrict__ khi, unsigned short* __restrict__ klo,
    unsigned short* __restrict__ vws)
{
    constexpr int XS = 40; // LDS stride (elems): 80B rows -> 16B aligned, ~2-way banks
    const int t = threadIdx.x, lane = t & 63, w = t >> 6;
    const int l15 = lane & 15, l4 = lane >> 4;
    const int b  = blockIdx.x >> 6;
    const int n0 = (blockIdx.x & 63) * 64;
    const float* xb = x + (size_t)b * CCH * NS;

    __shared__ unsigned short xh[64][XS]; // x tile transposed [n][c] hi
    __shared__ unsigned short xl[64][XS]; // lo

    f32x4 accv[4][4]; // [af][nf]
    f32x4 accq[4];    // [nf]
#pragma unroll
    for (int a = 0; a < 4; ++a)
#pragma unroll
        for (int n = 0; n < 4; ++n)
#pragma unroll
            for (int r = 0; r < 4; ++r) accv[a][n][r] = 0.f;
#pragma unroll
    for (int n = 0; n < 4; ++n)
#pragma unroll
        for (int r = 0; r < 4; ++r) accq[n][r] = 0.f;

    const float* Wqk = (w < 4) ? Wq : Wk;
    const int oq0 = (w & 3) * 16;
    const int stg_c = t >> 4;        // 0..31 within chunk
    const int stg_n = (t & 15) * 4;  // 0..60

    for (int cc = 0; cc < 16; ++cc) {
        // stage 32-channel chunk of x, transposed, split hi/lo
        f32x4 xv = *(const f32x4*)&xb[(size_t)(cc * 32 + stg_c) * NS + n0 + stg_n];
#pragma unroll
        for (int u = 0; u < 4; ++u) {
            unsigned short h = bf16_rne(xv[u]);
            xh[stg_n + u][stg_c] = h;
            xl[stg_n + u][stg_c] = bf16_rne(xv[u] - bf16_f(h));
        }
        __syncthreads();

        bf16x8 bh[4], bl[4];
#pragma unroll
        for (int nf = 0; nf < 4; ++nf) {
            bh[nf] = *(const bf16x8*)&xh[nf * 16 + l15][l4 * 8];
            bl[nf] = *(const bf16x8*)&xl[nf * 16 + l15][l4 * 8];
        }
        const int c8 = cc * 32 + l4 * 8;

        // v: plain bf16 (hi only) — error budget allows
#pragma unroll
        for (int af = 0; af < 4; ++af) {
            const float* wp = &Wv[(size_t)(w * 64 + af * 16 + l15) * CCH + c8];
            f32x4 wa = *(const f32x4*)wp;
            f32x4 wb = *(const f32x4*)(wp + 4);
            bf16x8 ah;
#pragma unroll
            for (int e = 0; e < 4; ++e) {
                ah[e]     = (short)bf16_rne(wa[e]);
                ah[e + 4] = (short)bf16_rne(wb[e]);
            }
#pragma unroll
            for (int nf = 0; nf < 4; ++nf)
                accv[af][nf] = MFMA16(ah, bh[nf], accv[af][nf]);
        }

        // q or k: 3-term split (Ahi*Bhi + Ahi*Blo + Alo*Bhi)
        {
            const float* wp = &Wqk[(size_t)(oq0 + l15) * CCH + c8];
            f32x4 wa = *(const f32x4*)wp;
            f32x4 wb = *(const f32x4*)(wp + 4);
            bf16x8 ah, al;
#pragma unroll
            for (int e = 0; e < 4; ++e) {
                unsigned short h = bf16_rne(wa[e]);
                ah[e] = (short)h; al[e] = (short)bf16_rne(wa[e] - bf16_f(h));
                h = bf16_rne(wb[e]);
                ah[e + 4] = (short)h; al[e + 4] = (short)bf16_rne(wb[e] - bf16_f(h));
            }
#pragma unroll
            for (int nf = 0; nf < 4; ++nf) {
                accq[nf] = MFMA16(ah, bh[nf], accq[nf]);
                accq[nf] = MFMA16(ah, bl[nf], accq[nf]);
                accq[nf] = MFMA16(al, bh[nf], accq[nf]);
            }
        }
        __syncthreads();
    }

    // ---- store v bf16 [B][C][N] ----
#pragma unroll
    for (int af = 0; af < 4; ++af) {
#pragma unroll
        for (int r = 0; r < 4; ++r) {
            const int o = w * 64 + af * 16 + l4 * 4 + r;
            const float bias = bv[o];
#pragma unroll
            for (int nf = 0; nf < 4; ++nf) {
                const int n = n0 + nf * 16 + l15;
                vws[(size_t)(b * CCH + o) * NS + n] = bf16_rne(accv[af][nf][r] + bias);
            }
        }
    }

    // ---- store q/k transposed + split: [B][N][64] hi & lo ----
    {
        unsigned short* hiT = (w < 4) ? qhi : khi;
        unsigned short* loT = (w < 4) ? qlo : klo;
        const float* bqk = (w < 4) ? bq : bk;
        float bias[4];
#pragma unroll
        for (int r = 0; r < 4; ++r) bias[r] = bqk[oq0 + l4 * 4 + r];
#pragma unroll
        for (int nf = 0; nf < 4; ++nf) {
            const int n = n0 + nf * 16 + l15;
            u16x4 hv, lv;
#pragma unroll
            for (int r = 0; r < 4; ++r) {
                float val = accq[nf][r] + bias[r];
                unsigned short h = bf16_rne(val);
                hv[r] = h;
                lv[r] = bf16_rne(val - bf16_f(h));
            }
            const size_t base = ((size_t)b * NS + n) * 64 + oq0 + l4 * 4;
            *(u16x4*)&hiT[base] = hv;
            *(u16x4*)&loT[base] = lv;
        }
    }
}

// ---------------------------------------------------------------------------
// Flash attention kernel. Grid: 256 blocks = b(4) x i-panel(64 rows each).
// Block: 512 thr = 8 waves. Wave w: QK frags (jf=w>>1, if=(w&1)*2+{0,1});
// PV channel slice c in [64w, 64w+64).
// ---------------------------------------------------------------------------
__global__ __launch_bounds__(512, 1) void attn_kernel(
    const float* __restrict__ x, const float* __restrict__ gamma,
    const unsigned short* __restrict__ qhi, const unsigned short* __restrict__ qlo,
    const unsigned short* __restrict__ khi, const unsigned short* __restrict__ klo,
    const unsigned short* __restrict__ vws, float* __restrict__ out)
{
    constexpr int PS = 72; // P lds row stride (elems): 144B rows
    const int t = threadIdx.x, lane = t & 63, w = t >> 6;
    const int l15 = lane & 15, l4 = lane >> 4;
    const int b  = blockIdx.x >> 6;
    const int i0 = (blockIdx.x & 63) * 64;

    __shared__ float Elds[64][65];            // E^T tile: [j][i]
    __shared__ unsigned short Plds[64][PS];   // P tile:   [i][j]
    __shared__ float m_run[64], l_run[64], sc_lds[64];

    if (t < 64) { m_run[t] = -1e30f; l_run[t] = 0.f; }

    // persistent Q B-frags for this wave's E columns
    const int jf = w >> 1;
    const int if_base = (w & 1) * 2;
    bf16x8 qh[2][2], ql[2][2]; // [qi][dstep]
#pragma unroll
    for (int qi = 0; qi < 2; ++qi) {
        const int i = i0 + (if_base + qi) * 16 + l15;
#pragma unroll
        for (int ds = 0; ds < 2; ++ds) {
            const size_t base = ((size_t)b * NS + i) * 64 + ds * 32 + l4 * 8;
            qh[qi][ds] = *(const bf16x8*)&qhi[base];
            ql[qi][ds] = *(const bf16x8*)&qlo[base];
        }
    }

    f32x4 O[4][4]; // [af(c)][if(i)]
#pragma unroll
    for (int a = 0; a < 4; ++a)
#pragma unroll
        for (int f = 0; f < 4; ++f)
#pragma unroll
            for (int r = 0; r < 4; ++r) O[a][f][r] = 0.f;

    const unsigned short* vb = vws + (size_t)b * CCH * NS;
    const size_t kbase = (size_t)b * NS * 64;

    __syncthreads(); // m_run/l_run init visible

    for (int jt = 0; jt < 64; ++jt) {
        const int j0 = jt * 64;

        // ---- phase 1: E^T frags (rows j, cols i), 3-term split ----
        f32x4 eacc[2];
#pragma unroll
        for (int qi = 0; qi < 2; ++qi)
#pragma unroll
            for (int r = 0; r < 4; ++r) eacc[qi][r] = 0.f;
        {
            const int j = j0 + jf * 16 + l15;
            bf16x8 kh[2], kl[2];
#pragma unroll
            for (int ds = 0; ds < 2; ++ds) {
                const size_t base = kbase + (size_t)j * 64 + ds * 32 + l4 * 8;
                kh[ds] = *(const bf16x8*)&khi[base];
                kl[ds] = *(const bf16x8*)&klo[base];
            }
#pragma unroll
            for (int qi = 0; qi < 2; ++qi)
#pragma unroll
                for (int ds = 0; ds < 2; ++ds) {
                    eacc[qi] = MFMA16(kh[ds], qh[qi][ds], eacc[qi]);
                    eacc[qi] = MFMA16(kh[ds], ql[qi][ds], eacc[qi]);
                    eacc[qi] = MFMA16(kl[ds], qh[qi][ds], eacc[qi]);
                }
        }
#pragma unroll
        for (int qi = 0; qi < 2; ++qi) {
            const int icol = (if_base + qi) * 16 + l15;
#pragma unroll
            for (int r = 0; r < 4; ++r)
                Elds[jf * 16 + l4 * 4 + r][icol] = eacc[qi][r];
        }
        __syncthreads(); // E tile complete

        // ---- phase 2: online softmax (8 lanes per row i) ----
        {
            const int il = t >> 3, jc = t & 7;
            float ev[8];
#pragma unroll
            for (int e = 0; e < 8; ++e) ev[e] = Elds[jc * 8 + e][il];
            float mx = ev[0];
#pragma unroll
            for (int e = 1; e < 8; ++e) mx = fmaxf(mx, ev[e]);
            mx = fmaxf(mx, __shfl_xor(mx, 1));
            mx = fmaxf(mx, __shfl_xor(mx, 2));
            mx = fmaxf(mx, __shfl_xor(mx, 4));
            const float m_old = m_run[il];
            const float m_new = fmaxf(m_old, mx);
            float s = 0.f;
            u16x8 pv;
#pragma unroll
            for (int e = 0; e < 8; ++e) {
                float p = __expf(ev[e] - m_new);
                s += p;
                pv[e] = bf16_rne(p);
            }
            s += __shfl_xor(s, 1);
            s += __shfl_xor(s, 2);
            s += __shfl_xor(s, 4);
            if (jc == 0) {
                const float sc = __expf(m_old - m_new);
                l_run[il] = l_run[il] * sc + s;
                m_run[il] = m_new;
                sc_lds[il] = sc;
            }
            *(u16x8*)&Plds[il][jc * 8] = pv;
        }
        __syncthreads(); // P tile + scales complete

        // ---- phase 3: rescale O, then PV ----
        {
            float scv[4];
#pragma unroll
            for (int f = 0; f < 4; ++f) scv[f] = sc_lds[f * 16 + l15];
#pragma unroll
            for (int a = 0; a < 4; ++a)
#pragma unroll
                for (int f = 0; f < 4; ++f)
#pragma unroll
                    for (int r = 0; r < 4; ++r) O[a][f][r] *= scv[f];
#pragma unroll
            for (int js = 0; js < 2; ++js) {
                bf16x8 pb[4];
#pragma unroll
                for (int f = 0; f < 4; ++f)
                    pb[f] = *(const bf16x8*)&Plds[f * 16 + l15][js * 32 + l4 * 8];
#pragma unroll
                for (int a = 0; a < 4; ++a) {
                    const int c = w * 64 + a * 16 + l15;
                    bf16x8 va = *(const bf16x8*)&vb[(size_t)c * NS + j0 + js * 32 + l4 * 8];
#pragma unroll
                    for (int f = 0; f < 4; ++f)
                        O[a][f] = MFMA16(va, pb[f], O[a][f]);
                }
            }
        }
        // no end barrier needed: next Elds write is fenced by this iter's two barriers
    }

    // ---- epilogue: out = gamma * O/l + x ----
    const float g = gamma[0];
    const float* xb = x + (size_t)b * CCH * NS;
    float linv[4];
#pragma unroll
    for (int f = 0; f < 4; ++f) linv[f] = 1.f / l_run[f * 16 + l15];
#pragma unroll
    for (int a = 0; a < 4; ++a) {
#pragma unroll
        for (int r = 0; r < 4; ++r) {
            const int c = w * 64 + a * 16 + l4 * 4 + r;
#pragma unroll
            for (int f = 0; f < 4; ++f) {
                const int i = i0 + f * 16 + l15;
                out[(size_t)(b * CCH + c) * NS + i] =
                    g * (O[a][f][r] * linv[f]) + xb[(size_t)c * NS + i];
            }
        }
    }
}

// ---------------------------------------------------------------------------
extern "C" void kernel_launch(void* const* d_in, const int* in_sizes, int n_in,
                              void* d_out, int out_size, void* d_ws, size_t ws_size,
                              hipStream_t stream)
{
    const float* x     = (const float*)d_in[0];
    const float* Wq    = (const float*)d_in[1];
    const float* bq    = (const float*)d_in[2];
    const float* Wk    = (const float*)d_in[3];
    const float* bk    = (const float*)d_in[4];
    const float* Wv    = (const float*)d_in[5];
    const float* bv    = (const float*)d_in[6];
    const float* gamma = (const float*)d_in[7];
    float* out = (float*)d_out;

    // ws layout (24 MB total)
    const size_t QK_ELEMS = (size_t)BB * NS * 64; // 1,048,576
    unsigned short* qhi = (unsigned short*)d_ws;
    unsigned short* qlo = qhi + QK_ELEMS;
    unsigned short* khi = qlo + QK_ELEMS;
    unsigned short* klo = khi + QK_ELEMS;
    unsigned short* v   = klo + QK_ELEMS;       // [4][512][4096] bf16 = 16 MB

    proj_kernel<<<256, 512, 0, stream>>>(x, Wq, bq, Wk, bk, Wv, bv,
                                         qhi, qlo, khi, klo, v);
    attn_kernel<<<256, 512, 0, stream>>>(x, gamma, qhi, qlo, khi, klo, v, out);
}